// Round 8
// baseline (249.205 us; speedup 1.0000x reference)
//
#include <hip/hip_runtime.h>
#include <hip/hip_bf16.h>

typedef __bf16 bf16;
typedef __bf16 bf16x4 __attribute__((ext_vector_type(4)));
typedef __bf16 bf16x8 __attribute__((ext_vector_type(8)));
typedef float f32x4 __attribute__((ext_vector_type(4)));

__device__ __forceinline__ void gload_lds16(const void* g, void* l) {
  __builtin_amdgcn_global_load_lds((__attribute__((address_space(1))) void*)(g),
                                   (__attribute__((address_space(3))) void*)(l), 16, 0, 0);
}
// raw 2^x (v_exp_f32 IS exp2)
__device__ __forceinline__ float fexp2(float x) {
  float r;
  asm volatile("v_exp_f32 %0, %1" : "=v"(r) : "v"(x));
  return r;
}
#define S_WAITCNT_VM(n) asm volatile("s_waitcnt vmcnt(" #n ")" ::: "memory")

// ---------------- diagnostic: encode ws_size into output if workspace too small ----
__global__ void k_diag(float* __restrict__ o, float v) { o[threadIdx.x] = v; }

// ---------------- fp32 -> bf16 convert (vectorized) ----------------
__global__ void k_cvt_bf16(const float* __restrict__ x, bf16* __restrict__ y, int n4) {
  int i = blockIdx.x * blockDim.x + threadIdx.x;
  if (i < n4) {
    float4 v = reinterpret_cast<const float4*>(x)[i];
    bf16x4 o = {(bf16)v.x, (bf16)v.y, (bf16)v.z, (bf16)v.w};
    reinterpret_cast<bf16x4*>(y)[i] = o;
  }
}

// ---------------- W (K x N fp32, row-major) -> Wt (N x K bf16) ----------------
__global__ void k_transpose_w(const float* __restrict__ W, bf16* __restrict__ Wt, int K, int N) {
  __shared__ float tile[32][33];
  int kb = blockIdx.x * 32, nb = blockIdx.y * 32;
  int tx = threadIdx.x & 31, ty = threadIdx.x >> 5;
#pragma unroll
  for (int i = 0; i < 32; i += 8)
    tile[ty + i][tx] = W[(size_t)(kb + ty + i) * N + nb + tx];
  __syncthreads();
#pragma unroll
  for (int i = 0; i < 32; i += 8)
    Wt[(size_t)(nb + ty + i) * K + kb + tx] = (bf16)tile[tx][ty + i];
}

// ---------------- V (cols 2560.. of Cqkv, stride 3072) -> Vt[b][kvh][HD][S] ----------------
__global__ void k_transpose_v(const bf16* __restrict__ Cq, bf16* __restrict__ Vt) {
  __shared__ bf16 tile[32][34];
  constexpr int S = 2048, CSTR = 3072;
  int sb = blockIdx.x * 32, db = blockIdx.y * 32, bh = blockIdx.z;  // bh = b*4+kvh
  int b = bh >> 2, kvh = bh & 3;
  int tx = threadIdx.x & 31, ty = threadIdx.x >> 5;
  const bf16* src = Cq + (size_t)b * S * CSTR + 2560 + kvh * 128;
#pragma unroll
  for (int i = 0; i < 32; i += 8)
    tile[ty + i][tx] = src[(size_t)(sb + ty + i) * CSTR + db + tx];
  __syncthreads();
  bf16* dst = Vt + (size_t)bh * 128 * S;
#pragma unroll
  for (int i = 0; i < 32; i += 8)
    dst[(size_t)(db + ty + i) * S + sb + tx] = tile[tx][ty + i];
}

// ---------------- 256x256 bf16 GEMM, m201-style 4-phase/K-tile counted-vmcnt ----------
// C[M,N] = A[M,K] * Bt[N,K]^T (Bt split at n=nsplit between B0/B1 bases).
// 8 waves (2M x 4N), wave tile 128x64, acc[8][4]. A held in regs across the K-tile
// (16 ds_read at p=0); per phase: 2 B ds_read + 16 MFMA. LDS 128 KiB:
//   A: 2buf x 4 units(64rx64k, 8KB)   B: 2buf x 4 phase-groups(4x16r x 64k, 8KB)
// Stage schedule (race-checked): at phase (kt,p): p=0 -> A(kt+1)unit3; p>=1 -> A(kt+2)unit(p-1);
// always B(kt+1)group p. vmcnt(6)/phase forces exactly the loads issued 4 phases ago;
// vmcnt(0) entering the last K-tile (tail accounting). Raw s_barrier, 1/phase.
template <typename OT>
__global__ __launch_bounds__(512) void k_gemm3(const bf16* __restrict__ A,
                                               const bf16* __restrict__ B0,
                                               const bf16* __restrict__ B1, int nsplit,
                                               OT* __restrict__ C, int Ncols, int Kd) {
  __shared__ __align__(16) bf16 lds_[65536];  // 128 KiB
  char* lds = (char*)lds_;
  const int t = threadIdx.x, w = t >> 6, l = t & 63;
  const int lr = l & 15, lk = l >> 4;
  const int gx = gridDim.x, nwg = gx * gridDim.y;
  const int flat = blockIdx.y * gx + blockIdx.x;
  const int vid = (flat & 7) * (nwg >> 3) + (flat >> 3);  // XCD swizzle (nwg%8==0)
  const int m0 = (vid % gx) * 256, n0 = (vid / gx) * 256;
  const int wm = w >> 2, wn = w & 3;
  const bf16* Bt = (n0 < nsplit) ? B0 + (size_t)n0 * Kd : B1 + (size_t)(n0 - nsplit) * Kd;
  const int nkt = Kd >> 6;
  // staging geometry: wave w writes subtile w (16r x 32k, 1KiB) of each 8KB unit
  const int srow = l >> 2;
  const int lch = (l & 3) ^ ((srow + (srow >> 2)) & 3);  // inverse swizzle on global source
  auto stA = [&](int tile, int unit) {
    if (tile >= nkt) return;
    const bf16* s = A + (size_t)(m0 + unit * 64 + (w >> 1) * 16 + srow) * Kd +
                    (tile << 6) + (w & 1) * 32 + lch * 8;
    gload_lds16(s, lds + (tile & 1) * 32768 + unit * 8192 + w * 1024);
  };
  auto stB = [&](int tile, int grp) {
    if (tile >= nkt) return;
    const bf16* s = Bt + (size_t)((w >> 1) * 64 + grp * 16 + srow) * Kd +
                    (tile << 6) + (w & 1) * 32 + lch * 8;
    gload_lds16(s, lds + 65536 + (tile & 1) * 32768 + grp * 8192 + w * 1024);
  };
  const int rdoff = lr * 64 + ((lk ^ ((lr + (lr >> 2)) & 3)) << 4);  // swizzled read

  f32x4 acc[8][4] = {};
  // prologue: A(0) fully + B(0)g0 first (phase-0 needs), then 6 more -> vmcnt(6) exact
  stA(0, 0); stA(0, 1); stA(0, 2); stA(0, 3);
  stB(0, 0);
  stA(1, 0); stB(0, 1); stA(1, 1); stB(0, 2); stA(1, 2); stB(0, 3);

  for (int kt = 0; kt < nkt; ++kt) {
    const int buf = kt & 1;
    const char* Ab = lds + buf * 32768;
    const char* Bb = lds + 65536 + buf * 32768;
    bf16x8 af[8][2];
#pragma unroll
    for (int p = 0; p < 4; ++p) {
      if (kt + 1 < nkt) { S_WAITCNT_VM(6); } else { S_WAITCNT_VM(0); }
      __builtin_amdgcn_sched_barrier(0);
      __builtin_amdgcn_s_barrier();
      __builtin_amdgcn_sched_barrier(0);
      if (p == 0) stA(kt + 1, 3); else stA(kt + 2, p - 1);
      stB(kt + 1, p);
      if (p == 0) {
#pragma unroll
        for (int i = 0; i < 8; ++i) {
          const char* ub = Ab + (wm * 2 + (i >> 2)) * 8192 + (i & 3) * 2048;
          af[i][0] = *reinterpret_cast<const bf16x8*>(ub + rdoff);
          af[i][1] = *reinterpret_cast<const bf16x8*>(ub + 1024 + rdoff);
        }
      }
      bf16x8 b0 = *reinterpret_cast<const bf16x8*>(Bb + p * 8192 + wn * 2048 + rdoff);
      bf16x8 b1 = *reinterpret_cast<const bf16x8*>(Bb + p * 8192 + wn * 2048 + 1024 + rdoff);
      __builtin_amdgcn_s_setprio(1);
#pragma unroll
      for (int i = 0; i < 8; ++i) {
        acc[i][p] = __builtin_amdgcn_mfma_f32_16x16x32_bf16(af[i][0], b0, acc[i][p], 0, 0, 0);
        acc[i][p] = __builtin_amdgcn_mfma_f32_16x16x32_bf16(af[i][1], b1, acc[i][p], 0, 0, 0);
      }
      __builtin_amdgcn_s_setprio(0);
      __builtin_amdgcn_sched_barrier(0);  // pin MFMAs (and lgkm waits) before next barrier
    }
  }
#pragma unroll
  for (int i = 0; i < 8; ++i)
#pragma unroll
    for (int j = 0; j < 4; ++j)
#pragma unroll
      for (int r = 0; r < 4; ++r) {
        int row = m0 + wm * 128 + i * 16 + lk * 4 + r;
        int col = n0 + wn * 64 + j * 16 + lr;
        if constexpr (sizeof(OT) == 4)
          C[(size_t)row * Ncols + col] = acc[i][j][r];
        else
          C[(size_t)row * Ncols + col] = (bf16)acc[i][j][r];
      }
}

// ---------------- RoPE in place (optionally folds score scale into Q) ----------------
__global__ void k_rope(bf16* __restrict__ X, const float* __restrict__ cs, const float* __restrict__ sn,
                       int nh, int rowstride, float scale, int total) {
  int idx = blockIdx.x * blockDim.x + threadIdx.x;
  if (idx >= total) return;
  int d = idx & 63;
  int th = idx >> 6;
  int h = th % nh;
  int tok = th / nh;
  size_t base = (size_t)tok * rowstride + h * 128;
  float c = cs[tok * 128 + d], s = sn[tok * 128 + d];
  float x1 = (float)X[base + d];
  float x2 = (float)X[base + d + 64];
  X[base + d] = (bf16)((x1 * c - x2 * s) * scale);
  X[base + d + 64] = (bf16)((x2 * c + x1 * s) * scale);
}

// ---------------- causal flash attention (round-5 verified), strides for fused Cqkv ----
// Q rows stride 3072 (cols 0..2047); K rows stride 3072 (KV base = Cqkv+2048);
// Vt[b*4+kvh][128][2048]; O = Ob stride 2048.
__global__ __launch_bounds__(256) void k_attn(const bf16* __restrict__ Q, const bf16* __restrict__ KV,
                                              const bf16* __restrict__ Vt, bf16* __restrict__ O) {
  constexpr int S = 2048, HD = 128, QSTR = 3072, OSTR = 2048;
  __shared__ __align__(16) bf16 sK[2][64 * 128];
  __shared__ __align__(16) bf16 sV[2][128 * 64];
  __shared__ __align__(16) bf16 sP[4][16][72];
  const int bid = blockIdx.x;
  const int vid = (bid & 7) * 64 + (bid >> 3);  // XCD swizzle: one (b,kvh) per XCD
  const int p = vid & 15, bh = vid >> 4;
  const int h = bh & 15, b = bh >> 4;
  const int t = threadIdx.x, w = t >> 6, l = t & 63;
  const int lr = l & 15, lk = l >> 4;
  const int kvh = h >> 2;
  const int swz = (lr & 7) << 4;

  const char* kbase = (const char*)(KV + (size_t)b * S * QSTR + kvh * HD);
  const int krow_l = w * 16 + (l >> 4);
  const int kcol_l = (l & 15) << 4;
  const char* vtbase = (const char*)(Vt + (size_t)(b * 4 + kvh) * HD * S);
  const int vrow_l = w * 32 + (l >> 3);
  const int vcol_l = (l & 7) << 4;
  char* sKb = (char*)sK;
  char* sVb = (char*)sV;
  auto stage = [&](int kvb, int buf) {
#pragma unroll
    for (int c = 0; c < 4; ++c) {
      const int krow = krow_l + c * 4;
      gload_lds16(kbase + (size_t)(kvb + krow) * (QSTR * 2) + (kcol_l ^ ((krow & 7) << 4)),
                  sKb + buf * 16384 + (w * 4 + c) * 1024);
      const int vrow = vrow_l + c * 8;
      gload_lds16(vtbase + (size_t)vrow * (S * 2) + kvb * 2 + (vcol_l ^ ((vrow & 7) << 4)),
                  sVb + buf * 16384 + (w * 4 + c) * 1024);
    }
  };

  for (int seg = 0; seg < 2; ++seg) {
    const int qtl = seg ? (31 - p) : p;
    const int qw = qtl * 64 + w * 16;
    const int ntiles = qtl + 1;
    int cur = 0;
    stage(0, 0);
    const bf16* Qp = Q + (size_t)(b * S + qw + lr) * QSTR + h * HD + lk * 8;
    bf16x8 qf[4];
#pragma unroll
    for (int i = 0; i < 4; ++i) qf[i] = *reinterpret_cast<const bf16x8*>(Qp + i * 32);
    f32x4 oacc[8] = {};
    float mrow[4] = {-3e38f, -3e38f, -3e38f, -3e38f};
    float lsum[4] = {0.f, 0.f, 0.f, 0.f};  // per-lane partials
    __syncthreads();
    for (int tt = 0; tt < ntiles; ++tt) {
      const int kvb = tt * 64;
      if (tt + 1 < ntiles) stage(kvb + 64, cur ^ 1);
      const char* sKc = sKb + cur * 16384;
      const char* sVc = sVb + cur * 16384;
      float pm[4][4];
#pragma unroll
      for (int c = 0; c < 4; ++c) {
        f32x4 s4 = {};
#pragma unroll
        for (int kf = 0; kf < 4; ++kf) {
          bf16x8 kf8 = *reinterpret_cast<const bf16x8*>(
              sKc + (c * 16 + lr) * 256 + (((kf * 64) + (lk << 4)) ^ swz));
          s4 = __builtin_amdgcn_mfma_f32_16x16x32_bf16(qf[kf], kf8, s4, 0, 0, 0);
        }
#pragma unroll
        for (int r = 0; r < 4; ++r) pm[c][r] = s4[r];
      }
      if (tt == ntiles - 1) {
#pragma unroll
        for (int c = 0; c < 4; ++c) {
          const int col = kvb + c * 16 + lr;
#pragma unroll
          for (int r = 0; r < 4; ++r)
            if (col > qw + lk * 4 + r) pm[c][r] = -3e38f;
        }
      }
      float pmax[4];
#pragma unroll
      for (int r = 0; r < 4; ++r)
        pmax[r] = fmaxf(fmaxf(pm[0][r], pm[1][r]), fmaxf(pm[2][r], pm[3][r]));
      bool hi = (pmax[0] > mrow[0] + 8.f) | (pmax[1] > mrow[1] + 8.f) |
                (pmax[2] > mrow[2] + 8.f) | (pmax[3] > mrow[3] + 8.f);
      if (__any(hi)) {
        float mx[4];
#pragma unroll
        for (int r = 0; r < 4; ++r) mx[r] = pmax[r];
#pragma unroll
        for (int off = 1; off < 16; off <<= 1)
#pragma unroll
          for (int r = 0; r < 4; ++r) mx[r] = fmaxf(mx[r], __shfl_xor(mx[r], off));
#pragma unroll
        for (int r = 0; r < 4; ++r) {
          float mn = fmaxf(mrow[r], mx[r]);
          float fac = fexp2(mrow[r] - mn);
          mrow[r] = mn;
          lsum[r] *= fac;
#pragma unroll
          for (int ch = 0; ch < 8; ++ch) oacc[ch][r] *= fac;
        }
      }
#pragma unroll
      for (int c = 0; c < 4; ++c)
#pragma unroll
        for (int r = 0; r < 4; ++r) pm[c][r] = fexp2(pm[c][r] - mrow[r]);
#pragma unroll
      for (int r = 0; r < 4; ++r)
        lsum[r] += (pm[0][r] + pm[1][r]) + (pm[2][r] + pm[3][r]);
#pragma unroll
      for (int c = 0; c < 4; ++c)
#pragma unroll
        for (int r = 0; r < 4; ++r) sP[w][lk * 4 + r][c * 16 + lr] = (bf16)pm[c][r];
      bf16x8 pf0 = *reinterpret_cast<const bf16x8*>(&sP[w][lr][lk * 8]);
      bf16x8 pf1 = *reinterpret_cast<const bf16x8*>(&sP[w][lr][32 + lk * 8]);
#pragma unroll
      for (int ch = 0; ch < 8; ++ch) {
        bf16x8 vf0 = *reinterpret_cast<const bf16x8*>(
            sVc + (ch * 16 + lr) * 128 + ((lk << 4) ^ swz));
        oacc[ch] = __builtin_amdgcn_mfma_f32_16x16x32_bf16(pf0, vf0, oacc[ch], 0, 0, 0);
        bf16x8 vf1 = *reinterpret_cast<const bf16x8*>(
            sVc + (ch * 16 + lr) * 128 + ((64 + (lk << 4)) ^ swz));
        oacc[ch] = __builtin_amdgcn_mfma_f32_16x16x32_bf16(pf1, vf1, oacc[ch], 0, 0, 0);
      }
      __syncthreads();
      cur ^= 1;
    }
#pragma unroll
    for (int off = 1; off < 16; off <<= 1)
#pragma unroll
      for (int r = 0; r < 4; ++r) lsum[r] += __shfl_xor(lsum[r], off);
    float inv[4];
#pragma unroll
    for (int r = 0; r < 4; ++r) inv[r] = 1.0f / lsum[r];
    bf16* Op = O + (size_t)(b * S + qw) * OSTR + h * HD;
#pragma unroll
    for (int ch = 0; ch < 8; ++ch)
#pragma unroll
      for (int r = 0; r < 4; ++r)
        Op[(size_t)(lk * 4 + r) * OSTR + ch * 16 + lr] = (bf16)(oacc[ch][r] * inv[r]);
  }
}

extern "C" void kernel_launch(void* const* d_in, const int* in_sizes, int n_in,
                              void* d_out, int out_size, void* d_ws, size_t ws_size,
                              hipStream_t stream) {
  const float* hs = (const float*)d_in[0];
  // d_in[1] = attention_mask: pure causal, applied analytically
  const float* cosb = (const float*)d_in[2];
  const float* sinb = (const float*)d_in[3];
  const float* Wq = (const float*)d_in[4];
  const float* Wk = (const float*)d_in[5];
  const float* Wv = (const float*)d_in[6];
  const float* Wo = (const float*)d_in[7];
  float* out = (float*)d_out;

  constexpr int B = 2, S = 2048, H = 2048, NH = 16, NKV = 4, HD = 128;
  constexpr int T = B * S;
  constexpr size_t MB = 1024 * 1024;

  // Workspace plan (d_ws 24 MiB):
  //   d_ws[ 0:16M) : Xb (bf16 X), reused as Ob after QKV projection
  //   d_ws[16:24M) : WtQ (8MB) -> later WtO (8MB)
  //   d_out[ 0:24M): Cqkv bf16 [4096][3072] (Q | K | V)
  //   d_out[24:28M): Vt [8][128][2048]
  //   d_out[28:32M): WtKV [1024][2048]
  //   (all d_out contents dead before O-GEMM overwrites d_out)
  const size_t ws_need = 24 * MB;
  if (ws_size < ws_need) {
    k_diag<<<1, 64, 0, stream>>>(out, 1000.0f + (float)(ws_size / MB));
    return;
  }
  bf16* Xb = (bf16*)d_ws;
  bf16* WtQ = (bf16*)((char*)d_ws + 16 * MB);  // also WtO slot later
  bf16* Ob = Xb;
  bf16* Cqkv = (bf16*)d_out;
  bf16* Vtb = (bf16*)((char*)d_out + 24 * MB);
  bf16* WtKV = (bf16*)((char*)d_out + 28 * MB);

  k_cvt_bf16<<<T * H / 4 / 256, 256, 0, stream>>>(hs, Xb, T * H / 4);

  // weight transposes: WtQ [2048][2048] in d_ws slot; WtKV [1024][2048] in d_out tail
  k_transpose_w<<<dim3(H / 32, H / 32), 256, 0, stream>>>(Wq, WtQ, H, H);
  k_transpose_w<<<dim3(H / 32, (NKV * HD) / 32), 256, 0, stream>>>(Wk, WtKV, H, NKV * HD);
  k_transpose_w<<<dim3(H / 32, (NKV * HD) / 32), 256, 0, stream>>>(Wv, WtKV + (size_t)(NKV * HD) * H, H, NKV * HD);

  // fused QKV projection: C[4096][3072], grid 16x12 = 192 blocks
  k_gemm3<bf16><<<dim3(16, 12), 512, 0, stream>>>(Xb, WtQ, WtKV, 2048, Cqkv, 3072, H);

  // V -> Vt (V gets no RoPE)
  k_transpose_v<<<dim3(S / 32, HD / 32, B * NKV), 256, 0, stream>>>(Cqkv, Vtb);

  // RoPE; Q folds log2(e)/sqrt(HD) so QK^T lands in log2 domain
  const float qscale = 0.12751743f;  // log2(e) / sqrt(128)
  k_rope<<<(T * NH * 64) / 256, 256, 0, stream>>>(Cqkv, cosb, sinb, NH, 3072, qscale, T * NH * 64);
  k_rope<<<(T * NKV * 64) / 256, 256, 0, stream>>>(Cqkv + 2048, cosb, sinb, NKV, 3072, 1.0f, T * NKV * 64);

  // Attention: reads Q/K (Cqkv) + Vt, writes Ob into d_ws (Xb dead)
  k_attn<<<512, 256, 0, stream>>>(Cqkv, Cqkv + 2048, Vtb, Ob);

  // O projection: reads only d_ws (Ob, WtO), writes all of d_out
  k_transpose_w<<<dim3(H / 32, H / 32), 256, 0, stream>>>(Wo, WtQ, H, H);
  k_gemm3<float><<<dim3(16, 8), 512, 0, stream>>>(Ob, WtQ, WtQ, 1 << 30, out, H, H);
}